// Round 11
// baseline (1294.510 us; speedup 1.0000x reference)
//
#include <hip/hip_runtime.h>

// ---------------------------------------------------------------------------
// Chamfer_Loss: chamfer(pred,tgt) + W_EDGE*edge + W_LAP*cotLap + W_NORMAL*nc
//               + W_VEL*chamfer(diff(pred), diff(tgt))
// B=2, N=8281 (g=91), fp32 in/out. Output: 1 scalar.
// R11: LDS-staged double-buffered B-tiles in the MFMA chamfer. R10 showed
//     MFMA 12.8% + VALU 28% + ~60% vmcnt dead time: 4 waves/block re-read the
//     same bfrag lines from L2 (540MB, ~250cyc under contention). Now each
//     block stages 8 tiles (8KB) once into LDS (global->reg->ds_write,
//     next batch in flight during compute), waves ds_read_b128 from LDS.
//     Also: finalize's last block writes d_out (write_out_k dropped).
// ---------------------------------------------------------------------------

typedef unsigned int uint32;
typedef __attribute__((ext_vector_type(8)))  short bf16x8;
typedef __attribute__((ext_vector_type(16))) float f32x16;

#define W_EDGE   0.5f
#define W_LAP    0.05f
#define W_NORMAL 0.01f
#define W_VEL    10.0f
#define BIGF     3.0e38f
#define RSTRIDE  8320      // padded row stride (>= 8281, 8320 = 65*128)

__device__ __forceinline__ unsigned short f2bf(float f){
    uint32 b = __float_as_uint(f);
    b += 0x7FFFu + ((b >> 16) & 1u);          // RNE
    return (unsigned short)(b >> 16);
}
__device__ __forceinline__ float bf2f(unsigned short h){
    return __uint_as_float(((uint32)h) << 16);
}

__device__ __forceinline__ float wave_sum(float v) {
#pragma unroll
    for (int o = 32; o > 0; o >>= 1) v += __shfl_down(v, o, 64);
    return v;
}

// ---------------------------------------------------------------------------
// B-fragment prep + workspace zeroing (fused; disjoint memory, same dispatch).
// combo c = dir*4 + ds*2 + b; dir 0: y-side = tgt, dir 1: y-side = pred.
// K-slot map (A-side in chamfer kernel):
//  k0-2: A=-2xh B=yh | k3-5: A=-2xl B=yh | k6-8: A=-2xh B=yl
//  k9:   A=xxh  B=1  | k10:  A=xxl B=1  | k11: A=1 B=yyh | k12: A=1 B=yyl
//  k13-15: 0.   acc = xx + yy - 2 x.y = d  (pad col: yy=BIG => never min)
// Lane l: col = l&31, holds k = (l>>5)*8 + i.
// ---------------------------------------------------------------------------
__global__ void bprep_k(const float* __restrict__ pred, const float* __restrict__ tgt,
                        int N, uint4* __restrict__ bfrag,
                        float* __restrict__ ws, int nzero)
{
    // grid-stride zero of [accum+counter | Lx | rowsum]
    {
        uint32* w = (uint32*)ws;
        for (int i = blockIdx.x * blockDim.x + threadIdx.x; i < nzero;
             i += gridDim.x * blockDim.x)
            w[i] = 0u;
    }

    const int NT = (N + 31) >> 5;
    const int gt = blockIdx.x * 4 + (threadIdx.x >> 6);
    if (gt >= 8 * NT) return;
    const int c = gt / NT, t = gt - c * NT;
    const int dir = c >> 2, ds = (c >> 1) & 1, b = c & 1;
    const int Np = N - ds;
    const int l = threadIdx.x & 63;
    const int col = t * 32 + (l & 31);
    const float* __restrict__ yb = (dir ? pred : tgt) + (size_t)b * N * 3;
    float y0 = 0.f, y1 = 0.f, y2 = 0.f;
    const bool valid = col < Np;
    if (valid){
        if (ds){
            y0 = yb[(col+1)*3+0] - yb[col*3+0];
            y1 = yb[(col+1)*3+1] - yb[col*3+1];
            y2 = yb[(col+1)*3+2] - yb[col*3+2];
        } else {
            y0 = yb[col*3+0]; y1 = yb[col*3+1]; y2 = yb[col*3+2];
        }
    }
    const float yy = fmaf(y0,y0, fmaf(y1,y1, y2*y2));
    unsigned short yh0=f2bf(y0), yh1=f2bf(y1), yh2=f2bf(y2);
    unsigned short yl0=f2bf(y0-bf2f(yh0)), yl1=f2bf(y1-bf2f(yh1)), yl2=f2bf(y2-bf2f(yh2));
    unsigned short yyh, yyl;
    if (valid){ yyh = f2bf(yy); yyl = f2bf(yy - bf2f(yyh)); }
    else      { yyh = f2bf(BIGF); yyl = 0; }
    const short ONE = (short)0x3F80;
    bf16x8 Bu;
    if (l < 32){        // k0-7
        Bu[0]=(short)yh0; Bu[1]=(short)yh1; Bu[2]=(short)yh2;
        Bu[3]=(short)yh0; Bu[4]=(short)yh1; Bu[5]=(short)yh2;
        Bu[6]=(short)yl0; Bu[7]=(short)yl1;
    } else {            // k8-15
        Bu[0]=(short)yl2; Bu[1]=ONE; Bu[2]=ONE; Bu[3]=(short)yyh; Bu[4]=(short)yyl;
        Bu[5]=0; Bu[6]=0; Bu[7]=0;
    }
    bfrag[(size_t)(c * NT + t) * 64 + l] = __builtin_bit_cast(uint4, Bu);
}

// ---------------------------------------------------------------------------
// MFMA chamfer, row-min only, LDS-staged. grid (65, 4, 8), 256 thr = 4 waves.
// Per batch of 8 tiles: all 256 threads load 2 uint4 -> ds_write (double
// buffered, next batch in flight during compute); each wave ds_read_b128 its
// lane's fragment per tile, pairs of MFMA -> 16 v_min3, sched_barrier pacing.
// rowpart[c][chunk][row] = min_{cols in chunk} d(row, col)
// ---------------------------------------------------------------------------
__global__ __launch_bounds__(256, 4)
void chamfer_mfma_k(const float* __restrict__ pred, const float* __restrict__ tgt,
                    int N, const uint4* __restrict__ bfrag,
                    float* __restrict__ rowpart)
{
    const int c = blockIdx.z;
    const int dir = c >> 2, ds = (c >> 1) & 1, b = c & 1;
    const int Np = N - ds;
    const int NT = (N + 31) >> 5;            // 259
    const int TC = (NT + 3) >> 2;            // 65
    const int t0 = blockIdx.y * TC;
    const int t1 = min(NT, t0 + TC);
    const int w = threadIdx.x >> 6, l = threadIdx.x & 63;
    const int h = l >> 5;
    const int grow = blockIdx.x * 128 + w * 32 + (l & 31);

    const float* __restrict__ xb = (dir ? tgt : pred) + (size_t)b * N * 3;
    float a0 = 0.f, a1 = 0.f, a2 = 0.f;
    const bool xvalid = grow < Np;
    if (xvalid){
        if (ds){
            a0 = xb[(grow+1)*3+0] - xb[grow*3+0];
            a1 = xb[(grow+1)*3+1] - xb[grow*3+1];
            a2 = xb[(grow+1)*3+2] - xb[grow*3+2];
        } else {
            a0 = xb[grow*3+0]; a1 = xb[grow*3+1]; a2 = xb[grow*3+2];
        }
    }
    const float xx = fmaf(a0,a0, fmaf(a1,a1, a2*a2));
    unsigned short xh0=f2bf(a0), xh1=f2bf(a1), xh2=f2bf(a2);
    unsigned short nxh0=f2bf(-2.f*bf2f(xh0)), nxh1=f2bf(-2.f*bf2f(xh1)), nxh2=f2bf(-2.f*bf2f(xh2));
    unsigned short nxl0=f2bf(-2.f*(a0-bf2f(xh0))), nxl1=f2bf(-2.f*(a1-bf2f(xh1))),
                   nxl2=f2bf(-2.f*(a2-bf2f(xh2)));
    unsigned short xxh=f2bf(xx), xxl=f2bf(xx-bf2f(xxh));
    const short ONE = (short)0x3F80;
    bf16x8 A;
    if (h == 0){   // k0-7
        A[0]=(short)nxh0; A[1]=(short)nxh1; A[2]=(short)nxh2;
        A[3]=(short)nxl0; A[4]=(short)nxl1; A[5]=(short)nxl2;
        A[6]=(short)nxh0; A[7]=(short)nxh1;
    } else {       // k8-15
        A[0]=(short)nxh2; A[1]=(short)xxh; A[2]=(short)xxl;
        A[3]=ONE; A[4]=ONE; A[5]=0; A[6]=0; A[7]=0;
    }

    f32x16 zacc;
#pragma unroll
    for (int r = 0; r < 16; ++r) zacc[r] = 0.f;
    float rm[16];
#pragma unroll
    for (int r = 0; r < 16; ++r) rm[r] = BIGF;

    __shared__ uint4 sB[2][512];             // 2 x 8 tiles x 64 lanes = 16KB
    const uint4* __restrict__ tb = bfrag + (size_t)c * NT * 64;

    const int i0 = threadIdx.x, i1 = threadIdx.x + 256;
    const int tl0 = i0 >> 6, ln0 = i0 & 63;
    const int tl1 = i1 >> 6, ln1 = i1 & 63;

    const int ntile = t1 - t0;
    const int nb = ntile >> 3;               // full 8-tile batches

    uint4 ra, rb;
    if (nb > 0){
        ra = tb[(size_t)(t0 + tl0) * 64 + ln0];
        rb = tb[(size_t)(t0 + tl1) * 64 + ln1];
        sB[0][i0] = ra; sB[0][i1] = rb;
    }
    __syncthreads();

    int cur = 0;
    for (int bt = 0; bt < nb; ++bt){
        const bool hn = (bt + 1 < nb);
        if (hn){
            const int tn = t0 + (bt + 1) * 8;
            ra = tb[(size_t)(tn + tl0) * 64 + ln0];
            rb = tb[(size_t)(tn + tl1) * 64 + ln1];
        }
        const uint4* __restrict__ sbl = &sB[cur][l];
        {
            const bf16x8 T0 = __builtin_bit_cast(bf16x8, sbl[0]);
            const bf16x8 T1 = __builtin_bit_cast(bf16x8, sbl[64]);
            const bf16x8 T2 = __builtin_bit_cast(bf16x8, sbl[128]);
            const bf16x8 T3 = __builtin_bit_cast(bf16x8, sbl[192]);
            {
                const f32x16 u0 = __builtin_amdgcn_mfma_f32_32x32x16_bf16(A, T0, zacc, 0, 0, 0);
                const f32x16 u1 = __builtin_amdgcn_mfma_f32_32x32x16_bf16(A, T1, zacc, 0, 0, 0);
#pragma unroll
                for (int r = 0; r < 16; ++r) rm[r] = fminf(fminf(rm[r], u0[r]), u1[r]);
            }
            __builtin_amdgcn_sched_barrier(0);
            const bf16x8 T4 = __builtin_bit_cast(bf16x8, sbl[256]);
            const bf16x8 T5 = __builtin_bit_cast(bf16x8, sbl[320]);
            {
                const f32x16 u2 = __builtin_amdgcn_mfma_f32_32x32x16_bf16(A, T2, zacc, 0, 0, 0);
                const f32x16 u3 = __builtin_amdgcn_mfma_f32_32x32x16_bf16(A, T3, zacc, 0, 0, 0);
#pragma unroll
                for (int r = 0; r < 16; ++r) rm[r] = fminf(fminf(rm[r], u2[r]), u3[r]);
            }
            __builtin_amdgcn_sched_barrier(0);
            const bf16x8 T6 = __builtin_bit_cast(bf16x8, sbl[384]);
            const bf16x8 T7 = __builtin_bit_cast(bf16x8, sbl[448]);
            {
                const f32x16 u4 = __builtin_amdgcn_mfma_f32_32x32x16_bf16(A, T4, zacc, 0, 0, 0);
                const f32x16 u5 = __builtin_amdgcn_mfma_f32_32x32x16_bf16(A, T5, zacc, 0, 0, 0);
#pragma unroll
                for (int r = 0; r < 16; ++r) rm[r] = fminf(fminf(rm[r], u4[r]), u5[r]);
            }
            __builtin_amdgcn_sched_barrier(0);
            {
                const f32x16 u6 = __builtin_amdgcn_mfma_f32_32x32x16_bf16(A, T6, zacc, 0, 0, 0);
                const f32x16 u7 = __builtin_amdgcn_mfma_f32_32x32x16_bf16(A, T7, zacc, 0, 0, 0);
#pragma unroll
                for (int r = 0; r < 16; ++r) rm[r] = fminf(fminf(rm[r], u6[r]), u7[r]);
            }
        }
        if (hn){ sB[cur ^ 1][i0] = ra; sB[cur ^ 1][i1] = rb; }
        __syncthreads();
        cur ^= 1;
    }

    // leftover tiles (<8) straight from global
    const uint4* __restrict__ bfp = tb + l;
    for (int t = t0 + nb * 8; t < t1; ++t){
        const bf16x8 T0 = __builtin_bit_cast(bf16x8, bfp[(size_t)t * 64]);
        const f32x16 u0 = __builtin_amdgcn_mfma_f32_32x32x16_bf16(A, T0, zacc, 0, 0, 0);
#pragma unroll
        for (int r = 0; r < 16; ++r) rm[r] = fminf(rm[r], u0[r]);
    }

    // row-min butterfly within each 32-lane half (cols live across lanes)
#pragma unroll
    for (int r = 0; r < 16; ++r){
        float v = rm[r];
        v = fminf(v, __shfl_xor(v, 1, 64));
        v = fminf(v, __shfl_xor(v, 2, 64));
        v = fminf(v, __shfl_xor(v, 4, 64));
        v = fminf(v, __shfl_xor(v, 8, 64));
        v = fminf(v, __shfl_xor(v, 16, 64));
        rm[r] = v;
    }
    float* __restrict__ rp = rowpart + (size_t)(c * 4 + blockIdx.y) * RSTRIDE;
#pragma unroll
    for (int r = 0; r < 16; ++r){             // static index only (no scratch)
        if ((l & 31) == r){
            const int rowl = (r & 3) + 8 * (r >> 2) + 4 * h;
            const int gr = blockIdx.x * 128 + w * 32 + rowl;
            if (gr < Np) rp[gr] = rm[r];
        }
    }
}

// edge loss + normal consistency + laplacian cot scatter, one dispatch.
__global__ void mesh_k(const float* __restrict__ pred,
                       const int* __restrict__ edges, int E,
                       const int* __restrict__ pairs, int P,
                       const int* __restrict__ faces, int F,
                       int N, int B, float scaleE, float scaleP,
                       float* __restrict__ Lx, float* __restrict__ rowsum,
                       float* __restrict__ accum)
{
    const int tE = B * E, tP = B * P, tF = B * F;
    const int total = tE + tP + tF;
    float se = 0.f, sp = 0.f;
    for (int idx = blockIdx.x * blockDim.x + threadIdx.x; idx < total;
         idx += gridDim.x * blockDim.x) {
        if (idx < tE) {
            const int b = idx / E;
            const int e = idx - b * E;
            const float* __restrict__ vb = pred + (size_t)b * N * 3;
            const int i0 = edges[e * 2 + 0], i1 = edges[e * 2 + 1];
            float dx = vb[i0 * 3 + 0] - vb[i1 * 3 + 0];
            float dy = vb[i0 * 3 + 1] - vb[i1 * 3 + 1];
            float dz = vb[i0 * 3 + 2] - vb[i1 * 3 + 2];
            se += fmaf(dx, dx, fmaf(dy, dy, dz * dz));
        } else if (idx < tE + tP) {
            const int q = idx - tE;
            const int b = q / P;
            const int p = q - b * P;
            const float* __restrict__ vb = pred + (size_t)b * N * 3;
            const int a0 = pairs[p * 4 + 0], a1 = pairs[p * 4 + 1];
            const int a2 = pairs[p * 4 + 2], a3 = pairs[p * 4 + 3];
            float p0x = vb[a0 * 3], p0y = vb[a0 * 3 + 1], p0z = vb[a0 * 3 + 2];
            float ex = vb[a1 * 3] - p0x, ey = vb[a1 * 3 + 1] - p0y, ez = vb[a1 * 3 + 2] - p0z;
            float ux = vb[a2 * 3] - p0x, uy = vb[a2 * 3 + 1] - p0y, uz = vb[a2 * 3 + 2] - p0z;
            float wx = vb[a3 * 3] - p0x, wy = vb[a3 * 3 + 1] - p0y, wz = vb[a3 * 3 + 2] - p0z;
            float n0x = ey * uz - ez * uy;
            float n0y = ez * ux - ex * uz;
            float n0z = ex * uy - ey * ux;
            float n1x = -(ey * wz - ez * wy);
            float n1y = -(ez * wx - ex * wz);
            float n1z = -(ex * wy - ey * wx);
            float dt = n0x * n1x + n0y * n1y + n0z * n1z;
            float l0 = sqrtf(n0x * n0x + n0y * n0y + n0z * n0z);
            float l1 = sqrtf(n1x * n1x + n1y * n1y + n1z * n1z);
            sp += 1.0f - dt / (fmaxf(l0, 1e-8f) * fmaxf(l1, 1e-8f));
        } else {
            const int q = idx - tE - tP;
            const int b = q / F;
            const int f = q - b * F;
            const float* __restrict__ vb = pred + (size_t)b * N * 3;
            const int i0 = faces[f * 3 + 0], i1 = faces[f * 3 + 1], i2 = faces[f * 3 + 2];
            float v0x = vb[i0 * 3], v0y = vb[i0 * 3 + 1], v0z = vb[i0 * 3 + 2];
            float v1x = vb[i1 * 3], v1y = vb[i1 * 3 + 1], v1z = vb[i1 * 3 + 2];
            float v2x = vb[i2 * 3], v2y = vb[i2 * 3 + 1], v2z = vb[i2 * 3 + 2];
            float ax = v1x - v2x, ay = v1y - v2y, az = v1z - v2z;
            float bx = v0x - v2x, by = v0y - v2y, bz = v0z - v2z;
            float cx = v0x - v1x, cy = v0y - v1y, cz = v0z - v1z;
            float A  = sqrtf(ax * ax + ay * ay + az * az);
            float Bl = sqrtf(bx * bx + by * by + bz * bz);
            float C  = sqrtf(cx * cx + cy * cy + cz * cz);
            float s2 = 0.5f * (A + Bl + C);
            float area = sqrtf(fmaxf(s2 * (s2 - A) * (s2 - Bl) * (s2 - C), 1e-12f));
            float A2 = A * A, B2 = Bl * Bl, C2 = C * C;
            float inv4a = 1.0f / (4.0f * area);
            float cota = (B2 + C2 - A2) * inv4a;
            float cotb = (A2 + C2 - B2) * inv4a;
            float cotc = (A2 + B2 - C2) * inv4a;

            float* __restrict__ Lb = Lx + (size_t)b * N * 3;
            float* __restrict__ rb = rowsum + (size_t)b * N;
            #define SCAT(i, j, wv)                                            \
                atomicAdd(&Lb[(i) * 3 + 0], (wv) * vb[(j) * 3 + 0]);          \
                atomicAdd(&Lb[(i) * 3 + 1], (wv) * vb[(j) * 3 + 1]);          \
                atomicAdd(&Lb[(i) * 3 + 2], (wv) * vb[(j) * 3 + 2]);          \
                atomicAdd(&rb[(i)], (wv));
            SCAT(i1, i2, cota) SCAT(i2, i1, cota)
            SCAT(i2, i0, cotb) SCAT(i0, i2, cotb)
            SCAT(i0, i1, cotc) SCAT(i1, i0, cotc)
            #undef SCAT
        }
    }
    se = wave_sum(se);
    sp = wave_sum(sp);
    if ((threadIdx.x & 63) == 0) atomicAdd(accum, fmaf(se, scaleE, sp * scaleP));
}

// rowpart 4-chunk min + clamp + lap residual; last block writes d_out.
__global__ void finalize_k(const float* __restrict__ rowpart,
                           const float* __restrict__ pred, const float* __restrict__ Lx,
                           const float* __restrict__ rowsum,
                           int N, float sMain, float sVel, float scaleL,
                           float* __restrict__ accum, float* __restrict__ out)
{
    const int total = 8 * N + 2 * N;
    float sm = 0.f, sv = 0.f, sl = 0.f;
    for (int idx = blockIdx.x * blockDim.x + threadIdx.x; idx < total;
         idx += gridDim.x * blockDim.x) {
        if (idx < 8 * N) {
            const int c = idx / N, i = idx - c * N;
            const int ds = (c >> 1) & 1;
            if (i < N - ds) {
                const float* rp = rowpart + (size_t)c * 4 * RSTRIDE;
                float v = fminf(fminf(rp[i], rp[RSTRIDE + i]),
                                fminf(rp[2*RSTRIDE + i], rp[3*RSTRIDE + i]));
                float d = fmaxf(v, 0.f);
                if (ds) sv += d; else sm += d;
            }
        } else {
            const int q = idx - 8 * N;       // B*N lap entries
            float rs = rowsum[q];
            float nw = rs > 0.f ? 1.0f / rs : 0.f;
            float rx = Lx[q*3+0]*nw - pred[q*3+0];
            float ry = Lx[q*3+1]*nw - pred[q*3+1];
            float rz = Lx[q*3+2]*nw - pred[q*3+2];
            sl += sqrtf(rx*rx + ry*ry + rz*rz);
        }
    }
    sm = wave_sum(sm); sv = wave_sum(sv); sl = wave_sum(sl);
    if ((threadIdx.x & 63) == 0)
        atomicAdd(accum, fmaf(sm, sMain, fmaf(sv, sVel, sl * scaleL)));

    // last block writes the output (accum[4] is the completion counter,
    // zeroed by bprep_k's ws-zero each launch)
    __syncthreads();
    if (threadIdx.x == 0){
        __threadfence();
        const uint32 prev = atomicAdd((uint32*)(accum + 4), 1u);
        if (prev == gridDim.x - 1)
            out[0] = atomicAdd(accum, 0.0f);   // coherent read of final sum
    }
}

extern "C" void kernel_launch(void* const* d_in, const int* in_sizes, int n_in,
                              void* d_out, int out_size, void* d_ws, size_t ws_size,
                              hipStream_t stream)
{
    const float* pred = (const float*)d_in[0];
    const float* tgt  = (const float*)d_in[1];
    const int* faces  = (const int*)d_in[2];
    const int* edges  = (const int*)d_in[3];
    const int* pairs  = (const int*)d_in[4];

    const int B = 2;
    const int N = in_sizes[0] / (3 * B);   // 8281
    const int F = in_sizes[2] / 3;
    const int E = in_sizes[3] / 2;
    const int P = in_sizes[4] / 4;
    const int NT = (N + 31) >> 5;          // 259

    // workspace layout (4B units):
    // [accum 8 (incl counter at +4)][Lx B*N*3][rowsum B*N][rowpart 32*RSTRIDE][bfrag]
    float* ws      = (float*)d_ws;
    float* accum   = ws;
    float* Lx      = ws + 8;
    float* rowsum  = Lx + (size_t)B * N * 3;
    float* rowpart = rowsum + (size_t)B * N;
    size_t off     = 8 + (size_t)B*N*3 + (size_t)B*N + (size_t)32*RSTRIDE;
    uint4* bfrag   = (uint4*)(ws + off);   // off*4 16B-aligned (off div by 4)

    const int nzero = 8 + B * N * 3 + B * N;

    bprep_k<<<dim3((8 * NT + 3) / 4), dim3(256), 0, stream>>>(pred, tgt, N, bfrag,
                                                              ws, nzero);

    chamfer_mfma_k<<<dim3((N + 127) / 128, 4, 8), dim3(256), 0, stream>>>(
        pred, tgt, N, bfrag, rowpart);

    mesh_k<<<128, dim3(256), 0, stream>>>(pred, edges, E, pairs, P, faces, F, N, B,
                                          W_EDGE / ((float)B * (float)E),
                                          W_NORMAL / ((float)B * (float)P),
                                          Lx, rowsum, accum);

    finalize_k<<<96, dim3(256), 0, stream>>>(rowpart, pred, Lx, rowsum, N,
                                             1.0f / ((float)B * (float)N),
                                             W_VEL / ((float)B * (float)(N - 1)),
                                             W_LAP / ((float)B * (float)N),
                                             accum, (float*)d_out);
}

// Round 12
// 131.771 us; speedup vs baseline: 9.8239x; 9.8239x over previous
//
#include <hip/hip_runtime.h>

// ---------------------------------------------------------------------------
// Chamfer_Loss: chamfer(pred,tgt) + W_EDGE*edge + W_LAP*cotLap + W_NORMAL*nc
//               + W_VEL*chamfer(diff(pred), diff(tgt))
// B=2, N=8281 (g=91), fp32 in/out. Output: 1 scalar.
// R12: revert R11's LDS+launch_bounds spill disaster (3.9GB scratch writes).
//     Back to R10's register path, but with an even/odd TWO-BATCH register
//     prefetch pipeline (statically named bufs, no movs, no sched_barrier):
//     batch B's 8 global_load_dwordx4 are in flight while batch A computes.
//     R10's sched_barriers serialized load->compute per batch (650cyc/tile
//     vs ~50 compute). Keep fused bprep-zero + finalize-writes-d_out.
// ---------------------------------------------------------------------------

typedef unsigned int uint32;
typedef __attribute__((ext_vector_type(8)))  short bf16x8;
typedef __attribute__((ext_vector_type(16))) float f32x16;

#define W_EDGE   0.5f
#define W_LAP    0.05f
#define W_NORMAL 0.01f
#define W_VEL    10.0f
#define BIGF     3.0e38f
#define RSTRIDE  8320      // padded row stride (>= 8281, 8320 = 65*128)

__device__ __forceinline__ unsigned short f2bf(float f){
    uint32 b = __float_as_uint(f);
    b += 0x7FFFu + ((b >> 16) & 1u);          // RNE
    return (unsigned short)(b >> 16);
}
__device__ __forceinline__ float bf2f(unsigned short h){
    return __uint_as_float(((uint32)h) << 16);
}

__device__ __forceinline__ float wave_sum(float v) {
#pragma unroll
    for (int o = 32; o > 0; o >>= 1) v += __shfl_down(v, o, 64);
    return v;
}

// ---------------------------------------------------------------------------
// B-fragment prep + workspace zeroing (fused; disjoint memory, same dispatch).
// combo c = dir*4 + ds*2 + b; dir 0: y-side = tgt, dir 1: y-side = pred.
// K-slot map (A-side in chamfer kernel):
//  k0-2: A=-2xh B=yh | k3-5: A=-2xl B=yh | k6-8: A=-2xh B=yl
//  k9:   A=xxh  B=1  | k10:  A=xxl B=1  | k11: A=1 B=yyh | k12: A=1 B=yyl
//  k13-15: 0.   acc = xx + yy - 2 x.y = d  (pad col: yy=BIG => never min)
// Lane l: col = l&31, holds k = (l>>5)*8 + i.
// ---------------------------------------------------------------------------
__global__ void bprep_k(const float* __restrict__ pred, const float* __restrict__ tgt,
                        int N, uint4* __restrict__ bfrag,
                        float* __restrict__ ws, int nzero)
{
    // grid-stride zero of [accum+counter | Lx | rowsum]
    {
        uint32* w = (uint32*)ws;
        for (int i = blockIdx.x * blockDim.x + threadIdx.x; i < nzero;
             i += gridDim.x * blockDim.x)
            w[i] = 0u;
    }

    const int NT = (N + 31) >> 5;
    const int gt = blockIdx.x * 4 + (threadIdx.x >> 6);
    if (gt >= 8 * NT) return;
    const int c = gt / NT, t = gt - c * NT;
    const int dir = c >> 2, ds = (c >> 1) & 1, b = c & 1;
    const int Np = N - ds;
    const int l = threadIdx.x & 63;
    const int col = t * 32 + (l & 31);
    const float* __restrict__ yb = (dir ? pred : tgt) + (size_t)b * N * 3;
    float y0 = 0.f, y1 = 0.f, y2 = 0.f;
    const bool valid = col < Np;
    if (valid){
        if (ds){
            y0 = yb[(col+1)*3+0] - yb[col*3+0];
            y1 = yb[(col+1)*3+1] - yb[col*3+1];
            y2 = yb[(col+1)*3+2] - yb[col*3+2];
        } else {
            y0 = yb[col*3+0]; y1 = yb[col*3+1]; y2 = yb[col*3+2];
        }
    }
    const float yy = fmaf(y0,y0, fmaf(y1,y1, y2*y2));
    unsigned short yh0=f2bf(y0), yh1=f2bf(y1), yh2=f2bf(y2);
    unsigned short yl0=f2bf(y0-bf2f(yh0)), yl1=f2bf(y1-bf2f(yh1)), yl2=f2bf(y2-bf2f(yh2));
    unsigned short yyh, yyl;
    if (valid){ yyh = f2bf(yy); yyl = f2bf(yy - bf2f(yyh)); }
    else      { yyh = f2bf(BIGF); yyl = 0; }
    const short ONE = (short)0x3F80;
    bf16x8 Bu;
    if (l < 32){        // k0-7
        Bu[0]=(short)yh0; Bu[1]=(short)yh1; Bu[2]=(short)yh2;
        Bu[3]=(short)yh0; Bu[4]=(short)yh1; Bu[5]=(short)yh2;
        Bu[6]=(short)yl0; Bu[7]=(short)yl1;
    } else {            // k8-15
        Bu[0]=(short)yl2; Bu[1]=ONE; Bu[2]=ONE; Bu[3]=(short)yyh; Bu[4]=(short)yyl;
        Bu[5]=0; Bu[6]=0; Bu[7]=0;
    }
    bfrag[(size_t)(c * NT + t) * 64 + l] = __builtin_bit_cast(uint4, Bu);
}

// ---------------------------------------------------------------------------
// MFMA chamfer, row-min only. grid (65, 4, 8), 256 thr = 4 waves.
// Even/odd two-batch register pipeline: while computing batch X, the 8
// global_load_dwordx4 of batch Y are in flight. Static buffer names, no
// rotation movs, no sched_barrier, no launch_bounds cap (avoid spill).
// rowpart[c][chunk][row] = min_{cols in chunk} d(row, col)
// ---------------------------------------------------------------------------
__global__ __launch_bounds__(256)
void chamfer_mfma_k(const float* __restrict__ pred, const float* __restrict__ tgt,
                    int N, const uint4* __restrict__ bfrag,
                    float* __restrict__ rowpart)
{
    const int c = blockIdx.z;
    const int dir = c >> 2, ds = (c >> 1) & 1, b = c & 1;
    const int Np = N - ds;
    const int NT = (N + 31) >> 5;            // 259
    const int TC = (NT + 3) >> 2;            // 65
    const int t0 = blockIdx.y * TC;
    const int t1 = min(NT, t0 + TC);
    const int w = threadIdx.x >> 6, l = threadIdx.x & 63;
    const int h = l >> 5;
    const int grow = blockIdx.x * 128 + w * 32 + (l & 31);

    const float* __restrict__ xb = (dir ? tgt : pred) + (size_t)b * N * 3;
    float a0 = 0.f, a1 = 0.f, a2 = 0.f;
    const bool xvalid = grow < Np;
    if (xvalid){
        if (ds){
            a0 = xb[(grow+1)*3+0] - xb[grow*3+0];
            a1 = xb[(grow+1)*3+1] - xb[grow*3+1];
            a2 = xb[(grow+1)*3+2] - xb[grow*3+2];
        } else {
            a0 = xb[grow*3+0]; a1 = xb[grow*3+1]; a2 = xb[grow*3+2];
        }
    }
    const float xx = fmaf(a0,a0, fmaf(a1,a1, a2*a2));
    unsigned short xh0=f2bf(a0), xh1=f2bf(a1), xh2=f2bf(a2);
    unsigned short nxh0=f2bf(-2.f*bf2f(xh0)), nxh1=f2bf(-2.f*bf2f(xh1)), nxh2=f2bf(-2.f*bf2f(xh2));
    unsigned short nxl0=f2bf(-2.f*(a0-bf2f(xh0))), nxl1=f2bf(-2.f*(a1-bf2f(xh1))),
                   nxl2=f2bf(-2.f*(a2-bf2f(xh2)));
    unsigned short xxh=f2bf(xx), xxl=f2bf(xx-bf2f(xxh));
    const short ONE = (short)0x3F80;
    bf16x8 A;
    if (h == 0){   // k0-7
        A[0]=(short)nxh0; A[1]=(short)nxh1; A[2]=(short)nxh2;
        A[3]=(short)nxl0; A[4]=(short)nxl1; A[5]=(short)nxl2;
        A[6]=(short)nxh0; A[7]=(short)nxh1;
    } else {       // k8-15
        A[0]=(short)nxh2; A[1]=(short)xxh; A[2]=(short)xxl;
        A[3]=ONE; A[4]=ONE; A[5]=0; A[6]=0; A[7]=0;
    }

    f32x16 zacc;
#pragma unroll
    for (int r = 0; r < 16; ++r) zacc[r] = 0.f;
    float rm[16];
#pragma unroll
    for (int r = 0; r < 16; ++r) rm[r] = BIGF;

    const uint4* __restrict__ bfp = bfrag + (size_t)c * NT * 64 + l;

    const int ntile = t1 - t0;
    const int nb = ntile >> 3;               // full 8-tile batches (8 for TC=65)

    uint4 Xa0, Xa1, Xa2, Xa3, Xa4, Xa5, Xa6, Xa7;
    uint4 Xb0, Xb1, Xb2, Xb3, Xb4, Xb5, Xb6, Xb7;

#define LOADB(P, tb_)                                                       \
    P##0 = bfp[(size_t)((tb_)+0)*64]; P##1 = bfp[(size_t)((tb_)+1)*64];     \
    P##2 = bfp[(size_t)((tb_)+2)*64]; P##3 = bfp[(size_t)((tb_)+3)*64];     \
    P##4 = bfp[(size_t)((tb_)+4)*64]; P##5 = bfp[(size_t)((tb_)+5)*64];     \
    P##6 = bfp[(size_t)((tb_)+6)*64]; P##7 = bfp[(size_t)((tb_)+7)*64];

#define PAIR(Ta, Tb)                                                        \
    {                                                                       \
        const f32x16 u0 = __builtin_amdgcn_mfma_f32_32x32x16_bf16(          \
            A, __builtin_bit_cast(bf16x8, Ta), zacc, 0, 0, 0);              \
        const f32x16 u1 = __builtin_amdgcn_mfma_f32_32x32x16_bf16(          \
            A, __builtin_bit_cast(bf16x8, Tb), zacc, 0, 0, 0);              \
        _Pragma("unroll")                                                   \
        for (int r = 0; r < 16; ++r)                                        \
            rm[r] = fminf(fminf(rm[r], u0[r]), u1[r]);                      \
    }

#define COMPB(P)                                                            \
    PAIR(P##0, P##1) PAIR(P##2, P##3) PAIR(P##4, P##5) PAIR(P##6, P##7)

    if (nb > 0){ LOADB(Xa, t0) }
    int bt = 0;
    for (; bt + 2 <= nb; bt += 2){
        LOADB(Xb, t0 + (bt + 1) * 8)         // in flight during COMPB(Xa)
        COMPB(Xa)
        if (bt + 2 < nb){ LOADB(Xa, t0 + (bt + 2) * 8) }
        COMPB(Xb)
    }
    if (bt < nb){ COMPB(Xa) }                // odd tail batch (already loaded)

#undef LOADB
#undef PAIR
#undef COMPB

    // leftover tiles (<8) straight from global
    for (int t = t0 + nb * 8; t < t1; ++t){
        const bf16x8 T0 = __builtin_bit_cast(bf16x8, bfp[(size_t)t * 64]);
        const f32x16 u0 = __builtin_amdgcn_mfma_f32_32x32x16_bf16(A, T0, zacc, 0, 0, 0);
#pragma unroll
        for (int r = 0; r < 16; ++r) rm[r] = fminf(rm[r], u0[r]);
    }

    // row-min butterfly within each 32-lane half (cols live across lanes)
#pragma unroll
    for (int r = 0; r < 16; ++r){
        float v = rm[r];
        v = fminf(v, __shfl_xor(v, 1, 64));
        v = fminf(v, __shfl_xor(v, 2, 64));
        v = fminf(v, __shfl_xor(v, 4, 64));
        v = fminf(v, __shfl_xor(v, 8, 64));
        v = fminf(v, __shfl_xor(v, 16, 64));
        rm[r] = v;
    }
    float* __restrict__ rp = rowpart + (size_t)(c * 4 + blockIdx.y) * RSTRIDE;
#pragma unroll
    for (int r = 0; r < 16; ++r){             // static index only (no scratch)
        if ((l & 31) == r){
            const int rowl = (r & 3) + 8 * (r >> 2) + 4 * h;
            const int gr = blockIdx.x * 128 + w * 32 + rowl;
            if (gr < Np) rp[gr] = rm[r];
        }
    }
}

// edge loss + normal consistency + laplacian cot scatter, one dispatch.
__global__ void mesh_k(const float* __restrict__ pred,
                       const int* __restrict__ edges, int E,
                       const int* __restrict__ pairs, int P,
                       const int* __restrict__ faces, int F,
                       int N, int B, float scaleE, float scaleP,
                       float* __restrict__ Lx, float* __restrict__ rowsum,
                       float* __restrict__ accum)
{
    const int tE = B * E, tP = B * P, tF = B * F;
    const int total = tE + tP + tF;
    float se = 0.f, sp = 0.f;
    for (int idx = blockIdx.x * blockDim.x + threadIdx.x; idx < total;
         idx += gridDim.x * blockDim.x) {
        if (idx < tE) {
            const int b = idx / E;
            const int e = idx - b * E;
            const float* __restrict__ vb = pred + (size_t)b * N * 3;
            const int i0 = edges[e * 2 + 0], i1 = edges[e * 2 + 1];
            float dx = vb[i0 * 3 + 0] - vb[i1 * 3 + 0];
            float dy = vb[i0 * 3 + 1] - vb[i1 * 3 + 1];
            float dz = vb[i0 * 3 + 2] - vb[i1 * 3 + 2];
            se += fmaf(dx, dx, fmaf(dy, dy, dz * dz));
        } else if (idx < tE + tP) {
            const int q = idx - tE;
            const int b = q / P;
            const int p = q - b * P;
            const float* __restrict__ vb = pred + (size_t)b * N * 3;
            const int a0 = pairs[p * 4 + 0], a1 = pairs[p * 4 + 1];
            const int a2 = pairs[p * 4 + 2], a3 = pairs[p * 4 + 3];
            float p0x = vb[a0 * 3], p0y = vb[a0 * 3 + 1], p0z = vb[a0 * 3 + 2];
            float ex = vb[a1 * 3] - p0x, ey = vb[a1 * 3 + 1] - p0y, ez = vb[a1 * 3 + 2] - p0z;
            float ux = vb[a2 * 3] - p0x, uy = vb[a2 * 3 + 1] - p0y, uz = vb[a2 * 3 + 2] - p0z;
            float wx = vb[a3 * 3] - p0x, wy = vb[a3 * 3 + 1] - p0y, wz = vb[a3 * 3 + 2] - p0z;
            float n0x = ey * uz - ez * uy;
            float n0y = ez * ux - ex * uz;
            float n0z = ex * uy - ey * ux;
            float n1x = -(ey * wz - ez * wy);
            float n1y = -(ez * wx - ex * wz);
            float n1z = -(ex * wy - ey * wx);
            float dt = n0x * n1x + n0y * n1y + n0z * n1z;
            float l0 = sqrtf(n0x * n0x + n0y * n0y + n0z * n0z);
            float l1 = sqrtf(n1x * n1x + n1y * n1y + n1z * n1z);
            sp += 1.0f - dt / (fmaxf(l0, 1e-8f) * fmaxf(l1, 1e-8f));
        } else {
            const int q = idx - tE - tP;
            const int b = q / F;
            const int f = q - b * F;
            const float* __restrict__ vb = pred + (size_t)b * N * 3;
            const int i0 = faces[f * 3 + 0], i1 = faces[f * 3 + 1], i2 = faces[f * 3 + 2];
            float v0x = vb[i0 * 3], v0y = vb[i0 * 3 + 1], v0z = vb[i0 * 3 + 2];
            float v1x = vb[i1 * 3], v1y = vb[i1 * 3 + 1], v1z = vb[i1 * 3 + 2];
            float v2x = vb[i2 * 3], v2y = vb[i2 * 3 + 1], v2z = vb[i2 * 3 + 2];
            float ax = v1x - v2x, ay = v1y - v2y, az = v1z - v2z;
            float bx = v0x - v2x, by = v0y - v2y, bz = v0z - v2z;
            float cx = v0x - v1x, cy = v0y - v1y, cz = v0z - v1z;
            float A  = sqrtf(ax * ax + ay * ay + az * az);
            float Bl = sqrtf(bx * bx + by * by + bz * bz);
            float C  = sqrtf(cx * cx + cy * cy + cz * cz);
            float s2 = 0.5f * (A + Bl + C);
            float area = sqrtf(fmaxf(s2 * (s2 - A) * (s2 - Bl) * (s2 - C), 1e-12f));
            float A2 = A * A, B2 = Bl * Bl, C2 = C * C;
            float inv4a = 1.0f / (4.0f * area);
            float cota = (B2 + C2 - A2) * inv4a;
            float cotb = (A2 + C2 - B2) * inv4a;
            float cotc = (A2 + B2 - C2) * inv4a;

            float* __restrict__ Lb = Lx + (size_t)b * N * 3;
            float* __restrict__ rb = rowsum + (size_t)b * N;
            #define SCAT(i, j, wv)                                            \
                atomicAdd(&Lb[(i) * 3 + 0], (wv) * vb[(j) * 3 + 0]);          \
                atomicAdd(&Lb[(i) * 3 + 1], (wv) * vb[(j) * 3 + 1]);          \
                atomicAdd(&Lb[(i) * 3 + 2], (wv) * vb[(j) * 3 + 2]);          \
                atomicAdd(&rb[(i)], (wv));
            SCAT(i1, i2, cota) SCAT(i2, i1, cota)
            SCAT(i2, i0, cotb) SCAT(i0, i2, cotb)
            SCAT(i0, i1, cotc) SCAT(i1, i0, cotc)
            #undef SCAT
        }
    }
    se = wave_sum(se);
    sp = wave_sum(sp);
    if ((threadIdx.x & 63) == 0) atomicAdd(accum, fmaf(se, scaleE, sp * scaleP));
}

// rowpart 4-chunk min + clamp + lap residual; last block writes d_out.
__global__ void finalize_k(const float* __restrict__ rowpart,
                           const float* __restrict__ pred, const float* __restrict__ Lx,
                           const float* __restrict__ rowsum,
                           int N, float sMain, float sVel, float scaleL,
                           float* __restrict__ accum, float* __restrict__ out)
{
    const int total = 8 * N + 2 * N;
    float sm = 0.f, sv = 0.f, sl = 0.f;
    for (int idx = blockIdx.x * blockDim.x + threadIdx.x; idx < total;
         idx += gridDim.x * blockDim.x) {
        if (idx < 8 * N) {
            const int c = idx / N, i = idx - c * N;
            const int ds = (c >> 1) & 1;
            if (i < N - ds) {
                const float* rp = rowpart + (size_t)c * 4 * RSTRIDE;
                float v = fminf(fminf(rp[i], rp[RSTRIDE + i]),
                                fminf(rp[2*RSTRIDE + i], rp[3*RSTRIDE + i]));
                float d = fmaxf(v, 0.f);
                if (ds) sv += d; else sm += d;
            }
        } else {
            const int q = idx - 8 * N;       // B*N lap entries
            float rs = rowsum[q];
            float nw = rs > 0.f ? 1.0f / rs : 0.f;
            float rx = Lx[q*3+0]*nw - pred[q*3+0];
            float ry = Lx[q*3+1]*nw - pred[q*3+1];
            float rz = Lx[q*3+2]*nw - pred[q*3+2];
            sl += sqrtf(rx*rx + ry*ry + rz*rz);
        }
    }
    sm = wave_sum(sm); sv = wave_sum(sv); sl = wave_sum(sl);
    if ((threadIdx.x & 63) == 0)
        atomicAdd(accum, fmaf(sm, sMain, fmaf(sv, sVel, sl * scaleL)));

    // last block writes the output (accum[4] is the completion counter,
    // zeroed by bprep_k's ws-zero each launch)
    __syncthreads();
    if (threadIdx.x == 0){
        __threadfence();
        const uint32 prev = atomicAdd((uint32*)(accum + 4), 1u);
        if (prev == gridDim.x - 1)
            out[0] = atomicAdd(accum, 0.0f);   // coherent read of final sum
    }
}

extern "C" void kernel_launch(void* const* d_in, const int* in_sizes, int n_in,
                              void* d_out, int out_size, void* d_ws, size_t ws_size,
                              hipStream_t stream)
{
    const float* pred = (const float*)d_in[0];
    const float* tgt  = (const float*)d_in[1];
    const int* faces  = (const int*)d_in[2];
    const int* edges  = (const int*)d_in[3];
    const int* pairs  = (const int*)d_in[4];

    const int B = 2;
    const int N = in_sizes[0] / (3 * B);   // 8281
    const int F = in_sizes[2] / 3;
    const int E = in_sizes[3] / 2;
    const int P = in_sizes[4] / 4;
    const int NT = (N + 31) >> 5;          // 259

    // workspace layout (4B units):
    // [accum 8 (incl counter at +4)][Lx B*N*3][rowsum B*N][rowpart 32*RSTRIDE][bfrag]
    float* ws      = (float*)d_ws;
    float* accum   = ws;
    float* Lx      = ws + 8;
    float* rowsum  = Lx + (size_t)B * N * 3;
    float* rowpart = rowsum + (size_t)B * N;
    size_t off     = 8 + (size_t)B*N*3 + (size_t)B*N + (size_t)32*RSTRIDE;
    uint4* bfrag   = (uint4*)(ws + off);   // off*4 16B-aligned (off div by 4)

    const int nzero = 8 + B * N * 3 + B * N;

    bprep_k<<<dim3((8 * NT + 3) / 4), dim3(256), 0, stream>>>(pred, tgt, N, bfrag,
                                                              ws, nzero);

    chamfer_mfma_k<<<dim3((N + 127) / 128, 4, 8), dim3(256), 0, stream>>>(
        pred, tgt, N, bfrag, rowpart);

    mesh_k<<<128, dim3(256), 0, stream>>>(pred, edges, E, pairs, P, faces, F, N, B,
                                          W_EDGE / ((float)B * (float)E),
                                          W_NORMAL / ((float)B * (float)P),
                                          Lx, rowsum, accum);

    finalize_k<<<96, dim3(256), 0, stream>>>(rowpart, pred, Lx, rowsum, N,
                                             1.0f / ((float)B * (float)N),
                                             W_VEL / ((float)B * (float)(N - 1)),
                                             W_LAP / ((float)B * (float)N),
                                             accum, (float*)d_out);
}

// Round 13
// 75.066 us; speedup vs baseline: 17.2451x; 1.7554x over previous
//
#include <hip/hip_runtime.h>

// ---------------------------------------------------------------------------
// Chamfer_Loss: chamfer(pred,tgt) + W_EDGE*edge + W_LAP*cotLap + W_NORMAL*nc
//               + W_VEL*chamfer(diff(pred), diff(tgt))
// B=2, N=8281 (g=91), fp32 in/out. Output: 1 scalar.
// R13: 2 A-fragments (64 rows) per wave on top of the proven R10 structure.
//     Each loaded B-tile feeds 2 MFMAs + 32 min3 (2x arithmetic intensity),
//     total bfrag traffic halves (270MB). R12 showed per-wave register
//     inflation kills occupancy-driven latency hiding; this adds only
//     A2 (+4) + rm2 (+16) regs, staging stays 8x uint4, live accs <= 2.
// ---------------------------------------------------------------------------

typedef unsigned int uint32;
typedef __attribute__((ext_vector_type(8)))  short bf16x8;
typedef __attribute__((ext_vector_type(16))) float f32x16;

#define W_EDGE   0.5f
#define W_LAP    0.05f
#define W_NORMAL 0.01f
#define W_VEL    10.0f
#define BIGF     3.0e38f
#define RSTRIDE  8320      // padded row stride (>= 8281, 8320 = 65*128)

__device__ __forceinline__ unsigned short f2bf(float f){
    uint32 b = __float_as_uint(f);
    b += 0x7FFFu + ((b >> 16) & 1u);          // RNE
    return (unsigned short)(b >> 16);
}
__device__ __forceinline__ float bf2f(unsigned short h){
    return __uint_as_float(((uint32)h) << 16);
}

__device__ __forceinline__ float wave_sum(float v) {
#pragma unroll
    for (int o = 32; o > 0; o >>= 1) v += __shfl_down(v, o, 64);
    return v;
}

// Build the A fragment for one 32-row group from (a0,a1,a2) [x pre-sign].
// K-slot map: k0-2:-2xh | k3-5:-2xl | k6-8:-2xh(dup wrap) | k9,k10: xxh,xxl
// | k11,k12: 1,1 | k13-15: 0
__device__ __forceinline__ bf16x8 make_A(float a0, float a1, float a2, int h){
    const float xx = fmaf(a0,a0, fmaf(a1,a1, a2*a2));
    unsigned short xh0=f2bf(a0), xh1=f2bf(a1), xh2=f2bf(a2);
    unsigned short nxh0=f2bf(-2.f*bf2f(xh0)), nxh1=f2bf(-2.f*bf2f(xh1)), nxh2=f2bf(-2.f*bf2f(xh2));
    unsigned short nxl0=f2bf(-2.f*(a0-bf2f(xh0))), nxl1=f2bf(-2.f*(a1-bf2f(xh1))),
                   nxl2=f2bf(-2.f*(a2-bf2f(xh2)));
    unsigned short xxh=f2bf(xx), xxl=f2bf(xx-bf2f(xxh));
    const short ONE = (short)0x3F80;
    bf16x8 A;
    if (h == 0){   // k0-7
        A[0]=(short)nxh0; A[1]=(short)nxh1; A[2]=(short)nxh2;
        A[3]=(short)nxl0; A[4]=(short)nxl1; A[5]=(short)nxl2;
        A[6]=(short)nxh0; A[7]=(short)nxh1;
    } else {       // k8-15
        A[0]=(short)nxh2; A[1]=(short)xxh; A[2]=(short)xxl;
        A[3]=ONE; A[4]=ONE; A[5]=0; A[6]=0; A[7]=0;
    }
    return A;
}

// ---------------------------------------------------------------------------
// B-fragment prep + workspace zeroing (fused; disjoint memory, same dispatch).
// combo c = dir*4 + ds*2 + b; dir 0: y-side = tgt, dir 1: y-side = pred.
// B K-slots: k0-5: yh yh | k6-8: yl | k9,k10: 1 | k11,k12: yyh,yyl | rest 0.
// acc = xx + yy - 2 x.y = d  (pad col: yy=BIG => never min)
// Lane l: col = l&31, holds k = (l>>5)*8 + i.
// ---------------------------------------------------------------------------
__global__ void bprep_k(const float* __restrict__ pred, const float* __restrict__ tgt,
                        int N, uint4* __restrict__ bfrag,
                        float* __restrict__ ws, int nzero)
{
    // grid-stride zero of [accum+counter | Lx | rowsum]
    {
        uint32* w = (uint32*)ws;
        for (int i = blockIdx.x * blockDim.x + threadIdx.x; i < nzero;
             i += gridDim.x * blockDim.x)
            w[i] = 0u;
    }

    const int NT = (N + 31) >> 5;
    const int gt = blockIdx.x * 4 + (threadIdx.x >> 6);
    if (gt >= 8 * NT) return;
    const int c = gt / NT, t = gt - c * NT;
    const int dir = c >> 2, ds = (c >> 1) & 1, b = c & 1;
    const int Np = N - ds;
    const int l = threadIdx.x & 63;
    const int col = t * 32 + (l & 31);
    const float* __restrict__ yb = (dir ? pred : tgt) + (size_t)b * N * 3;
    float y0 = 0.f, y1 = 0.f, y2 = 0.f;
    const bool valid = col < Np;
    if (valid){
        if (ds){
            y0 = yb[(col+1)*3+0] - yb[col*3+0];
            y1 = yb[(col+1)*3+1] - yb[col*3+1];
            y2 = yb[(col+1)*3+2] - yb[col*3+2];
        } else {
            y0 = yb[col*3+0]; y1 = yb[col*3+1]; y2 = yb[col*3+2];
        }
    }
    const float yy = fmaf(y0,y0, fmaf(y1,y1, y2*y2));
    unsigned short yh0=f2bf(y0), yh1=f2bf(y1), yh2=f2bf(y2);
    unsigned short yl0=f2bf(y0-bf2f(yh0)), yl1=f2bf(y1-bf2f(yh1)), yl2=f2bf(y2-bf2f(yh2));
    unsigned short yyh, yyl;
    if (valid){ yyh = f2bf(yy); yyl = f2bf(yy - bf2f(yyh)); }
    else      { yyh = f2bf(BIGF); yyl = 0; }
    const short ONE = (short)0x3F80;
    bf16x8 Bu;
    if (l < 32){        // k0-7
        Bu[0]=(short)yh0; Bu[1]=(short)yh1; Bu[2]=(short)yh2;
        Bu[3]=(short)yh0; Bu[4]=(short)yh1; Bu[5]=(short)yh2;
        Bu[6]=(short)yl0; Bu[7]=(short)yl1;
    } else {            // k8-15
        Bu[0]=(short)yl2; Bu[1]=ONE; Bu[2]=ONE; Bu[3]=(short)yyh; Bu[4]=(short)yyl;
        Bu[5]=0; Bu[6]=0; Bu[7]=0;
    }
    bfrag[(size_t)(c * NT + t) * 64 + l] = __builtin_bit_cast(uint4, Bu);
}

// ---------------------------------------------------------------------------
// MFMA chamfer, row-min only. grid (33 x-blocks, 4 y-chunks, 8 combos),
// 256 thr = 4 waves; wave w owns 64 rows (2 A-fragments), sweeps its chunk's
// tiles in 8-load batches; each tile -> 2 MFMAs (A1,A2) + 32 min3, paired
// with sched_barrier pacing (R10's proven anti-hoist structure).
// rowpart[c][chunk][row] = min_{cols in chunk} d(row, col)
// ---------------------------------------------------------------------------
__global__ __launch_bounds__(256)
void chamfer_mfma_k(const float* __restrict__ pred, const float* __restrict__ tgt,
                    int N, const uint4* __restrict__ bfrag,
                    float* __restrict__ rowpart)
{
    const int c = blockIdx.z;
    const int dir = c >> 2, ds = (c >> 1) & 1, b = c & 1;
    const int Np = N - ds;
    const int NT = (N + 31) >> 5;            // 259
    const int TC = (NT + 3) >> 2;            // 65
    const int t0 = blockIdx.y * TC;
    const int t1 = min(NT, t0 + TC);
    const int w = threadIdx.x >> 6, l = threadIdx.x & 63;
    const int h = l >> 5;
    const int rbase = blockIdx.x * 256 + w * 64 + (l & 31);

    const float* __restrict__ xb = (dir ? tgt : pred) + (size_t)b * N * 3;
    float a0[2], a1[2], a2[2];
#pragma unroll
    for (int j = 0; j < 2; ++j){
        const int gr = rbase + j * 32;
        float v0 = 0.f, v1 = 0.f, v2 = 0.f;
        if (gr < Np){
            if (ds){
                v0 = xb[(gr+1)*3+0] - xb[gr*3+0];
                v1 = xb[(gr+1)*3+1] - xb[gr*3+1];
                v2 = xb[(gr+1)*3+2] - xb[gr*3+2];
            } else {
                v0 = xb[gr*3+0]; v1 = xb[gr*3+1]; v2 = xb[gr*3+2];
            }
        }
        a0[j] = v0; a1[j] = v1; a2[j] = v2;
    }
    const bf16x8 A1 = make_A(a0[0], a1[0], a2[0], h);
    const bf16x8 A2 = make_A(a0[1], a1[1], a2[1], h);

    f32x16 zacc;
#pragma unroll
    for (int r = 0; r < 16; ++r) zacc[r] = 0.f;
    float rm1[16], rm2[16];
#pragma unroll
    for (int r = 0; r < 16; ++r){ rm1[r] = BIGF; rm2[r] = BIGF; }

    const uint4* __restrict__ bfp = bfrag + (size_t)c * NT * 64 + l;

    const int ntile = t1 - t0;
    const int nb = ntile >> 3;               // full 8-tile batches

#define PAIR2(Ta, Tb)                                                       \
    {                                                                       \
        const f32x16 u0 = __builtin_amdgcn_mfma_f32_32x32x16_bf16(          \
            A1, __builtin_bit_cast(bf16x8, Ta), zacc, 0, 0, 0);             \
        const f32x16 u1 = __builtin_amdgcn_mfma_f32_32x32x16_bf16(          \
            A1, __builtin_bit_cast(bf16x8, Tb), zacc, 0, 0, 0);             \
        _Pragma("unroll")                                                   \
        for (int r = 0; r < 16; ++r)                                        \
            rm1[r] = fminf(fminf(rm1[r], u0[r]), u1[r]);                    \
    }                                                                       \
    __builtin_amdgcn_sched_barrier(0);                                      \
    {                                                                       \
        const f32x16 u2 = __builtin_amdgcn_mfma_f32_32x32x16_bf16(          \
            A2, __builtin_bit_cast(bf16x8, Ta), zacc, 0, 0, 0);             \
        const f32x16 u3 = __builtin_amdgcn_mfma_f32_32x32x16_bf16(          \
            A2, __builtin_bit_cast(bf16x8, Tb), zacc, 0, 0, 0);             \
        _Pragma("unroll")                                                   \
        for (int r = 0; r < 16; ++r)                                        \
            rm2[r] = fminf(fminf(rm2[r], u2[r]), u3[r]);                    \
    }                                                                       \
    __builtin_amdgcn_sched_barrier(0);

    int t = t0;
    for (int bt = 0; bt < nb; ++bt, t += 8){
        const uint4 T0 = bfp[(size_t)(t+0)*64];
        const uint4 T1 = bfp[(size_t)(t+1)*64];
        const uint4 T2 = bfp[(size_t)(t+2)*64];
        const uint4 T3 = bfp[(size_t)(t+3)*64];
        const uint4 T4 = bfp[(size_t)(t+4)*64];
        const uint4 T5 = bfp[(size_t)(t+5)*64];
        const uint4 T6 = bfp[(size_t)(t+6)*64];
        const uint4 T7 = bfp[(size_t)(t+7)*64];
        PAIR2(T0, T1)
        PAIR2(T2, T3)
        PAIR2(T4, T5)
        PAIR2(T6, T7)
    }
#undef PAIR2

    // leftover tiles (<8)
    for (; t < t1; ++t){
        const bf16x8 T0 = __builtin_bit_cast(bf16x8, bfp[(size_t)t * 64]);
        const f32x16 u0 = __builtin_amdgcn_mfma_f32_32x32x16_bf16(A1, T0, zacc, 0, 0, 0);
        const f32x16 u1 = __builtin_amdgcn_mfma_f32_32x32x16_bf16(A2, T0, zacc, 0, 0, 0);
#pragma unroll
        for (int r = 0; r < 16; ++r){
            rm1[r] = fminf(rm1[r], u0[r]);
            rm2[r] = fminf(rm2[r], u1[r]);
        }
    }

    // row-min butterfly within each 32-lane half (cols live across lanes)
#pragma unroll
    for (int r = 0; r < 16; ++r){
        float v = rm1[r];
        v = fminf(v, __shfl_xor(v, 1, 64));
        v = fminf(v, __shfl_xor(v, 2, 64));
        v = fminf(v, __shfl_xor(v, 4, 64));
        v = fminf(v, __shfl_xor(v, 8, 64));
        v = fminf(v, __shfl_xor(v, 16, 64));
        rm1[r] = v;
        float u = rm2[r];
        u = fminf(u, __shfl_xor(u, 1, 64));
        u = fminf(u, __shfl_xor(u, 2, 64));
        u = fminf(u, __shfl_xor(u, 4, 64));
        u = fminf(u, __shfl_xor(u, 8, 64));
        u = fminf(u, __shfl_xor(u, 16, 64));
        rm2[r] = u;
    }
    float* __restrict__ rp = rowpart + (size_t)(c * 4 + blockIdx.y) * RSTRIDE;
#pragma unroll
    for (int r = 0; r < 16; ++r){             // static index only (no scratch)
        if ((l & 31) == r){
            const int rowl = (r & 3) + 8 * (r >> 2) + 4 * h;
            const int g1 = blockIdx.x * 256 + w * 64 + rowl;
            if (g1 < Np)      rp[g1]      = rm1[r];
            if (g1 + 32 < Np) rp[g1 + 32] = rm2[r];
        }
    }
}

// edge loss + normal consistency + laplacian cot scatter, one dispatch.
__global__ void mesh_k(const float* __restrict__ pred,
                       const int* __restrict__ edges, int E,
                       const int* __restrict__ pairs, int P,
                       const int* __restrict__ faces, int F,
                       int N, int B, float scaleE, float scaleP,
                       float* __restrict__ Lx, float* __restrict__ rowsum,
                       float* __restrict__ accum)
{
    const int tE = B * E, tP = B * P, tF = B * F;
    const int total = tE + tP + tF;
    float se = 0.f, sp = 0.f;
    for (int idx = blockIdx.x * blockDim.x + threadIdx.x; idx < total;
         idx += gridDim.x * blockDim.x) {
        if (idx < tE) {
            const int b = idx / E;
            const int e = idx - b * E;
            const float* __restrict__ vb = pred + (size_t)b * N * 3;
            const int i0 = edges[e * 2 + 0], i1 = edges[e * 2 + 1];
            float dx = vb[i0 * 3 + 0] - vb[i1 * 3 + 0];
            float dy = vb[i0 * 3 + 1] - vb[i1 * 3 + 1];
            float dz = vb[i0 * 3 + 2] - vb[i1 * 3 + 2];
            se += fmaf(dx, dx, fmaf(dy, dy, dz * dz));
        } else if (idx < tE + tP) {
            const int q = idx - tE;
            const int b = q / P;
            const int p = q - b * P;
            const float* __restrict__ vb = pred + (size_t)b * N * 3;
            const int a0 = pairs[p * 4 + 0], a1 = pairs[p * 4 + 1];
            const int a2 = pairs[p * 4 + 2], a3 = pairs[p * 4 + 3];
            float p0x = vb[a0 * 3], p0y = vb[a0 * 3 + 1], p0z = vb[a0 * 3 + 2];
            float ex = vb[a1 * 3] - p0x, ey = vb[a1 * 3 + 1] - p0y, ez = vb[a1 * 3 + 2] - p0z;
            float ux = vb[a2 * 3] - p0x, uy = vb[a2 * 3 + 1] - p0y, uz = vb[a2 * 3 + 2] - p0z;
            float wx = vb[a3 * 3] - p0x, wy = vb[a3 * 3 + 1] - p0y, wz = vb[a3 * 3 + 2] - p0z;
            float n0x = ey * uz - ez * uy;
            float n0y = ez * ux - ex * uz;
            float n0z = ex * uy - ey * ux;
            float n1x = -(ey * wz - ez * wy);
            float n1y = -(ez * wx - ex * wz);
            float n1z = -(ex * wy - ey * wx);
            float dt = n0x * n1x + n0y * n1y + n0z * n1z;
            float l0 = sqrtf(n0x * n0x + n0y * n0y + n0z * n0z);
            float l1 = sqrtf(n1x * n1x + n1y * n1y + n1z * n1z);
            sp += 1.0f - dt / (fmaxf(l0, 1e-8f) * fmaxf(l1, 1e-8f));
        } else {
            const int q = idx - tE - tP;
            const int b = q / F;
            const int f = q - b * F;
            const float* __restrict__ vb = pred + (size_t)b * N * 3;
            const int i0 = faces[f * 3 + 0], i1 = faces[f * 3 + 1], i2 = faces[f * 3 + 2];
            float v0x = vb[i0 * 3], v0y = vb[i0 * 3 + 1], v0z = vb[i0 * 3 + 2];
            float v1x = vb[i1 * 3], v1y = vb[i1 * 3 + 1], v1z = vb[i1 * 3 + 2];
            float v2x = vb[i2 * 3], v2y = vb[i2 * 3 + 1], v2z = vb[i2 * 3 + 2];
            float ax = v1x - v2x, ay = v1y - v2y, az = v1z - v2z;
            float bx = v0x - v2x, by = v0y - v2y, bz = v0z - v2z;
            float cx = v0x - v1x, cy = v0y - v1y, cz = v0z - v1z;
            float A  = sqrtf(ax * ax + ay * ay + az * az);
            float Bl = sqrtf(bx * bx + by * by + bz * bz);
            float C  = sqrtf(cx * cx + cy * cy + cz * cz);
            float s2 = 0.5f * (A + Bl + C);
            float area = sqrtf(fmaxf(s2 * (s2 - A) * (s2 - Bl) * (s2 - C), 1e-12f));
            float A2 = A * A, B2 = Bl * Bl, C2 = C * C;
            float inv4a = 1.0f / (4.0f * area);
            float cota = (B2 + C2 - A2) * inv4a;
            float cotb = (A2 + C2 - B2) * inv4a;
            float cotc = (A2 + B2 - C2) * inv4a;

            float* __restrict__ Lb = Lx + (size_t)b * N * 3;
            float* __restrict__ rb = rowsum + (size_t)b * N;
            #define SCAT(i, j, wv)                                            \
                atomicAdd(&Lb[(i) * 3 + 0], (wv) * vb[(j) * 3 + 0]);          \
                atomicAdd(&Lb[(i) * 3 + 1], (wv) * vb[(j) * 3 + 1]);          \
                atomicAdd(&Lb[(i) * 3 + 2], (wv) * vb[(j) * 3 + 2]);          \
                atomicAdd(&rb[(i)], (wv));
            SCAT(i1, i2, cota) SCAT(i2, i1, cota)
            SCAT(i2, i0, cotb) SCAT(i0, i2, cotb)
            SCAT(i0, i1, cotc) SCAT(i1, i0, cotc)
            #undef SCAT
        }
    }
    se = wave_sum(se);
    sp = wave_sum(sp);
    if ((threadIdx.x & 63) == 0) atomicAdd(accum, fmaf(se, scaleE, sp * scaleP));
}

// rowpart 4-chunk min + clamp + lap residual; last block writes d_out.
__global__ void finalize_k(const float* __restrict__ rowpart,
                           const float* __restrict__ pred, const float* __restrict__ Lx,
                           const float* __restrict__ rowsum,
                           int N, float sMain, float sVel, float scaleL,
                           float* __restrict__ accum, float* __restrict__ out)
{
    const int total = 8 * N + 2 * N;
    float sm = 0.f, sv = 0.f, sl = 0.f;
    for (int idx = blockIdx.x * blockDim.x + threadIdx.x; idx < total;
         idx += gridDim.x * blockDim.x) {
        if (idx < 8 * N) {
            const int c = idx / N, i = idx - c * N;
            const int ds = (c >> 1) & 1;
            if (i < N - ds) {
                const float* rp = rowpart + (size_t)c * 4 * RSTRIDE;
                float v = fminf(fminf(rp[i], rp[RSTRIDE + i]),
                                fminf(rp[2*RSTRIDE + i], rp[3*RSTRIDE + i]));
                float d = fmaxf(v, 0.f);
                if (ds) sv += d; else sm += d;
            }
        } else {
            const int q = idx - 8 * N;       // B*N lap entries
            float rs = rowsum[q];
            float nw = rs > 0.f ? 1.0f / rs : 0.f;
            float rx = Lx[q*3+0]*nw - pred[q*3+0];
            float ry = Lx[q*3+1]*nw - pred[q*3+1];
            float rz = Lx[q*3+2]*nw - pred[q*3+2];
            sl += sqrtf(rx*rx + ry*ry + rz*rz);
        }
    }
    sm = wave_sum(sm); sv = wave_sum(sv); sl = wave_sum(sl);
    if ((threadIdx.x & 63) == 0)
        atomicAdd(accum, fmaf(sm, sMain, fmaf(sv, sVel, sl * scaleL)));

    // last block writes the output (accum[4] is the completion counter,
    // zeroed by bprep_k's ws-zero each launch)
    __syncthreads();
    if (threadIdx.x == 0){
        __threadfence();
        const uint32 prev = atomicAdd((uint32*)(accum + 4), 1u);
        if (prev == gridDim.x - 1)
            out[0] = atomicAdd(accum, 0.0f);   // coherent read of final sum
    }
}

extern "C" void kernel_launch(void* const* d_in, const int* in_sizes, int n_in,
                              void* d_out, int out_size, void* d_ws, size_t ws_size,
                              hipStream_t stream)
{
    const float* pred = (const float*)d_in[0];
    const float* tgt  = (const float*)d_in[1];
    const int* faces  = (const int*)d_in[2];
    const int* edges  = (const int*)d_in[3];
    const int* pairs  = (const int*)d_in[4];

    const int B = 2;
    const int N = in_sizes[0] / (3 * B);   // 8281
    const int F = in_sizes[2] / 3;
    const int E = in_sizes[3] / 2;
    const int P = in_sizes[4] / 4;
    const int NT = (N + 31) >> 5;          // 259

    // workspace layout (4B units):
    // [accum 8 (incl counter at +4)][Lx B*N*3][rowsum B*N][rowpart 32*RSTRIDE][bfrag]
    float* ws      = (float*)d_ws;
    float* accum   = ws;
    float* Lx      = ws + 8;
    float* rowsum  = Lx + (size_t)B * N * 3;
    float* rowpart = rowsum + (size_t)B * N;
    size_t off     = 8 + (size_t)B*N*3 + (size_t)B*N + (size_t)32*RSTRIDE;
    uint4* bfrag   = (uint4*)(ws + off);   // off*4 16B-aligned (off div by 4)

    const int nzero = 8 + B * N * 3 + B * N;

    bprep_k<<<dim3((8 * NT + 3) / 4), dim3(256), 0, stream>>>(pred, tgt, N, bfrag,
                                                              ws, nzero);

    chamfer_mfma_k<<<dim3((N + 255) / 256, 4, 8), dim3(256), 0, stream>>>(
        pred, tgt, N, bfrag, rowpart);

    mesh_k<<<128, dim3(256), 0, stream>>>(pred, edges, E, pairs, P, faces, F, N, B,
                                          W_EDGE / ((float)B * (float)E),
                                          W_NORMAL / ((float)B * (float)P),
                                          Lx, rowsum, accum);

    finalize_k<<<96, dim3(256), 0, stream>>>(rowpart, pred, Lx, rowsum, N,
                                             1.0f / ((float)B * (float)N),
                                             W_VEL / ((float)B * (float)(N - 1)),
                                             W_LAP / ((float)B * (float)N),
                                             accum, (float*)d_out);
}

// Round 14
// 73.606 us; speedup vs baseline: 17.5871x; 1.0198x over previous
//
#include <hip/hip_runtime.h>

// ---------------------------------------------------------------------------
// Chamfer_Loss: chamfer(pred,tgt) + W_EDGE*edge + W_LAP*cotLap + W_NORMAL*nc
//               + W_VEL*chamfer(diff(pred), diff(tgt))
// B=2, N=8281 (g=91), fp32 in/out. Output: 1 scalar.
// R14: occupancy push on the proven R10 structure. R9-R13 data: duration
//     tracks occupancy (dur*occ ~ const), so per-wave register state is THE
//     lever. Single-tile compute units (1 MFMA -> 16 v_min -> sched_barrier)
//     cap live accumulators at 1 (16 AGPR vs R10's 32). Everything else
//     identical to R10 (best total 71.5us).
// ---------------------------------------------------------------------------

typedef unsigned int uint32;
typedef __attribute__((ext_vector_type(8)))  short bf16x8;
typedef __attribute__((ext_vector_type(16))) float f32x16;

#define W_EDGE   0.5f
#define W_LAP    0.05f
#define W_NORMAL 0.01f
#define W_VEL    10.0f
#define BIGF     3.0e38f
#define RSTRIDE  8320      // padded row stride (>= 8281, 8320 = 65*128)

__device__ __forceinline__ unsigned short f2bf(float f){
    uint32 b = __float_as_uint(f);
    b += 0x7FFFu + ((b >> 16) & 1u);          // RNE
    return (unsigned short)(b >> 16);
}
__device__ __forceinline__ float bf2f(unsigned short h){
    return __uint_as_float(((uint32)h) << 16);
}

__device__ __forceinline__ float wave_sum(float v) {
#pragma unroll
    for (int o = 32; o > 0; o >>= 1) v += __shfl_down(v, o, 64);
    return v;
}

// ---------------------------------------------------------------------------
// B-fragment prep + workspace zeroing (fused; disjoint memory, same dispatch).
// combo c = dir*4 + ds*2 + b; dir 0: y-side = tgt, dir 1: y-side = pred.
// K-slot map (A-side in chamfer kernel):
//  k0-2: A=-2xh B=yh | k3-5: A=-2xl B=yh | k6-8: A=-2xh B=yl
//  k9:   A=xxh  B=1  | k10:  A=xxl B=1  | k11: A=1 B=yyh | k12: A=1 B=yyl
//  k13-15: 0.   acc = xx + yy - 2 x.y = d  (pad col: yy=BIG => never min)
// Lane l: col = l&31, holds k = (l>>5)*8 + i.
// ---------------------------------------------------------------------------
__global__ void bprep_k(const float* __restrict__ pred, const float* __restrict__ tgt,
                        int N, uint4* __restrict__ bfrag,
                        float* __restrict__ ws, int nzero)
{
    // grid-stride zero of [accum+counter | Lx | rowsum]
    {
        uint32* w = (uint32*)ws;
        for (int i = blockIdx.x * blockDim.x + threadIdx.x; i < nzero;
             i += gridDim.x * blockDim.x)
            w[i] = 0u;
    }

    const int NT = (N + 31) >> 5;
    const int gt = blockIdx.x * 4 + (threadIdx.x >> 6);
    if (gt >= 8 * NT) return;
    const int c = gt / NT, t = gt - c * NT;
    const int dir = c >> 2, ds = (c >> 1) & 1, b = c & 1;
    const int Np = N - ds;
    const int l = threadIdx.x & 63;
    const int col = t * 32 + (l & 31);
    const float* __restrict__ yb = (dir ? pred : tgt) + (size_t)b * N * 3;
    float y0 = 0.f, y1 = 0.f, y2 = 0.f;
    const bool valid = col < Np;
    if (valid){
        if (ds){
            y0 = yb[(col+1)*3+0] - yb[col*3+0];
            y1 = yb[(col+1)*3+1] - yb[col*3+1];
            y2 = yb[(col+1)*3+2] - yb[col*3+2];
        } else {
            y0 = yb[col*3+0]; y1 = yb[col*3+1]; y2 = yb[col*3+2];
        }
    }
    const float yy = fmaf(y0,y0, fmaf(y1,y1, y2*y2));
    unsigned short yh0=f2bf(y0), yh1=f2bf(y1), yh2=f2bf(y2);
    unsigned short yl0=f2bf(y0-bf2f(yh0)), yl1=f2bf(y1-bf2f(yh1)), yl2=f2bf(y2-bf2f(yh2));
    unsigned short yyh, yyl;
    if (valid){ yyh = f2bf(yy); yyl = f2bf(yy - bf2f(yyh)); }
    else      { yyh = f2bf(BIGF); yyl = 0; }
    const short ONE = (short)0x3F80;
    bf16x8 Bu;
    if (l < 32){        // k0-7
        Bu[0]=(short)yh0; Bu[1]=(short)yh1; Bu[2]=(short)yh2;
        Bu[3]=(short)yh0; Bu[4]=(short)yh1; Bu[5]=(short)yh2;
        Bu[6]=(short)yl0; Bu[7]=(short)yl1;
    } else {            // k8-15
        Bu[0]=(short)yl2; Bu[1]=ONE; Bu[2]=ONE; Bu[3]=(short)yyh; Bu[4]=(short)yyl;
        Bu[5]=0; Bu[6]=0; Bu[7]=0;
    }
    bfrag[(size_t)(c * NT + t) * 64 + l] = __builtin_bit_cast(uint4, Bu);
}

// ---------------------------------------------------------------------------
// MFMA chamfer, row-min only. grid (65, 4, 8), 256 thr = 4 waves.
// 8-tile load batches (8 global_load_dwordx4 in flight); compute one tile at
// a time {1 MFMA -> 16 v_min} with sched_barrier(0) after each tile, capping
// live accumulators at 1 (16 AGPR) for maximum occupancy.
// rowpart[c][chunk][row] = min_{cols in chunk} d(row, col)
// ---------------------------------------------------------------------------
__global__ __launch_bounds__(256)
void chamfer_mfma_k(const float* __restrict__ pred, const float* __restrict__ tgt,
                    int N, const uint4* __restrict__ bfrag,
                    float* __restrict__ rowpart)
{
    const int c = blockIdx.z;
    const int dir = c >> 2, ds = (c >> 1) & 1, b = c & 1;
    const int Np = N - ds;
    const int NT = (N + 31) >> 5;            // 259
    const int TC = (NT + 3) >> 2;            // 65
    const int t0 = blockIdx.y * TC;
    const int t1 = min(NT, t0 + TC);
    const int w = threadIdx.x >> 6, l = threadIdx.x & 63;
    const int h = l >> 5;
    const int grow = blockIdx.x * 128 + w * 32 + (l & 31);

    const float* __restrict__ xb = (dir ? tgt : pred) + (size_t)b * N * 3;
    float a0 = 0.f, a1 = 0.f, a2 = 0.f;
    const bool xvalid = grow < Np;
    if (xvalid){
        if (ds){
            a0 = xb[(grow+1)*3+0] - xb[grow*3+0];
            a1 = xb[(grow+1)*3+1] - xb[grow*3+1];
            a2 = xb[(grow+1)*3+2] - xb[grow*3+2];
        } else {
            a0 = xb[grow*3+0]; a1 = xb[grow*3+1]; a2 = xb[grow*3+2];
        }
    }
    const float xx = fmaf(a0,a0, fmaf(a1,a1, a2*a2));
    unsigned short xh0=f2bf(a0), xh1=f2bf(a1), xh2=f2bf(a2);
    unsigned short nxh0=f2bf(-2.f*bf2f(xh0)), nxh1=f2bf(-2.f*bf2f(xh1)), nxh2=f2bf(-2.f*bf2f(xh2));
    unsigned short nxl0=f2bf(-2.f*(a0-bf2f(xh0))), nxl1=f2bf(-2.f*(a1-bf2f(xh1))),
                   nxl2=f2bf(-2.f*(a2-bf2f(xh2)));
    unsigned short xxh=f2bf(xx), xxl=f2bf(xx-bf2f(xxh));
    const short ONE = (short)0x3F80;
    bf16x8 A;
    if (h == 0){   // k0-7
        A[0]=(short)nxh0; A[1]=(short)nxh1; A[2]=(short)nxh2;
        A[3]=(short)nxl0; A[4]=(short)nxl1; A[5]=(short)nxl2;
        A[6]=(short)nxh0; A[7]=(short)nxh1;
    } else {       // k8-15
        A[0]=(short)nxh2; A[1]=(short)xxh; A[2]=(short)xxl;
        A[3]=ONE; A[4]=ONE; A[5]=0; A[6]=0; A[7]=0;
    }

    f32x16 zacc;
#pragma unroll
    for (int r = 0; r < 16; ++r) zacc[r] = 0.f;
    float rm[16];
#pragma unroll
    for (int r = 0; r < 16; ++r) rm[r] = BIGF;

    const uint4* __restrict__ bfp = bfrag + (size_t)c * NT * 64 + l;

    const int ntile = t1 - t0;
    const int nb = ntile >> 3;               // full 8-tile batches

#define ONE_TILE(T)                                                         \
    {                                                                       \
        const f32x16 u = __builtin_amdgcn_mfma_f32_32x32x16_bf16(           \
            A, __builtin_bit_cast(bf16x8, T), zacc, 0, 0, 0);               \
        _Pragma("unroll")                                                   \
        for (int r = 0; r < 16; ++r) rm[r] = fminf(rm[r], u[r]);            \
    }                                                                       \
    __builtin_amdgcn_sched_barrier(0);

    int t = t0;
    for (int bt = 0; bt < nb; ++bt, t += 8){
        // issue all 8 tile loads up-front (independent, stay in flight)
        const uint4 T0 = bfp[(size_t)(t+0)*64];
        const uint4 T1 = bfp[(size_t)(t+1)*64];
        const uint4 T2 = bfp[(size_t)(t+2)*64];
        const uint4 T3 = bfp[(size_t)(t+3)*64];
        const uint4 T4 = bfp[(size_t)(t+4)*64];
        const uint4 T5 = bfp[(size_t)(t+5)*64];
        const uint4 T6 = bfp[(size_t)(t+6)*64];
        const uint4 T7 = bfp[(size_t)(t+7)*64];
        ONE_TILE(T0) ONE_TILE(T1) ONE_TILE(T2) ONE_TILE(T3)
        ONE_TILE(T4) ONE_TILE(T5) ONE_TILE(T6) ONE_TILE(T7)
    }
#undef ONE_TILE

    // leftover tiles (<8)
    for (; t < t1; ++t){
        const bf16x8 T0 = __builtin_bit_cast(bf16x8, bfp[(size_t)t * 64]);
        const f32x16 u0 = __builtin_amdgcn_mfma_f32_32x32x16_bf16(A, T0, zacc, 0, 0, 0);
#pragma unroll
        for (int r = 0; r < 16; ++r) rm[r] = fminf(rm[r], u0[r]);
    }

    // row-min butterfly within each 32-lane half (cols live across lanes)
#pragma unroll
    for (int r = 0; r < 16; ++r){
        float v = rm[r];
        v = fminf(v, __shfl_xor(v, 1, 64));
        v = fminf(v, __shfl_xor(v, 2, 64));
        v = fminf(v, __shfl_xor(v, 4, 64));
        v = fminf(v, __shfl_xor(v, 8, 64));
        v = fminf(v, __shfl_xor(v, 16, 64));
        rm[r] = v;
    }
    float* __restrict__ rp = rowpart + (size_t)(c * 4 + blockIdx.y) * RSTRIDE;
#pragma unroll
    for (int r = 0; r < 16; ++r){             // static index only (no scratch)
        if ((l & 31) == r){
            const int rowl = (r & 3) + 8 * (r >> 2) + 4 * h;
            const int gr = blockIdx.x * 128 + w * 32 + rowl;
            if (gr < Np) rp[gr] = rm[r];
        }
    }
}

// edge loss + normal consistency + laplacian cot scatter, one dispatch.
__global__ void mesh_k(const float* __restrict__ pred,
                       const int* __restrict__ edges, int E,
                       const int* __restrict__ pairs, int P,
                       const int* __restrict__ faces, int F,
                       int N, int B, float scaleE, float scaleP,
                       float* __restrict__ Lx, float* __restrict__ rowsum,
                       float* __restrict__ accum)
{
    const int tE = B * E, tP = B * P, tF = B * F;
    const int total = tE + tP + tF;
    float se = 0.f, sp = 0.f;
    for (int idx = blockIdx.x * blockDim.x + threadIdx.x; idx < total;
         idx += gridDim.x * blockDim.x) {
        if (idx < tE) {
            const int b = idx / E;
            const int e = idx - b * E;
            const float* __restrict__ vb = pred + (size_t)b * N * 3;
            const int i0 = edges[e * 2 + 0], i1 = edges[e * 2 + 1];
            float dx = vb[i0 * 3 + 0] - vb[i1 * 3 + 0];
            float dy = vb[i0 * 3 + 1] - vb[i1 * 3 + 1];
            float dz = vb[i0 * 3 + 2] - vb[i1 * 3 + 2];
            se += fmaf(dx, dx, fmaf(dy, dy, dz * dz));
        } else if (idx < tE + tP) {
            const int q = idx - tE;
            const int b = q / P;
            const int p = q - b * P;
            const float* __restrict__ vb = pred + (size_t)b * N * 3;
            const int a0 = pairs[p * 4 + 0], a1 = pairs[p * 4 + 1];
            const int a2 = pairs[p * 4 + 2], a3 = pairs[p * 4 + 3];
            float p0x = vb[a0 * 3], p0y = vb[a0 * 3 + 1], p0z = vb[a0 * 3 + 2];
            float ex = vb[a1 * 3] - p0x, ey = vb[a1 * 3 + 1] - p0y, ez = vb[a1 * 3 + 2] - p0z;
            float ux = vb[a2 * 3] - p0x, uy = vb[a2 * 3 + 1] - p0y, uz = vb[a2 * 3 + 2] - p0z;
            float wx = vb[a3 * 3] - p0x, wy = vb[a3 * 3 + 1] - p0y, wz = vb[a3 * 3 + 2] - p0z;
            float n0x = ey * uz - ez * uy;
            float n0y = ez * ux - ex * uz;
            float n0z = ex * uy - ey * ux;
            float n1x = -(ey * wz - ez * wy);
            float n1y = -(ez * wx - ex * wz);
            float n1z = -(ex * wy - ey * wx);
            float dt = n0x * n1x + n0y * n1y + n0z * n1z;
            float l0 = sqrtf(n0x * n0x + n0y * n0y + n0z * n0z);
            float l1 = sqrtf(n1x * n1x + n1y * n1y + n1z * n1z);
            sp += 1.0f - dt / (fmaxf(l0, 1e-8f) * fmaxf(l1, 1e-8f));
        } else {
            const int q = idx - tE - tP;
            const int b = q / F;
            const int f = q - b * F;
            const float* __restrict__ vb = pred + (size_t)b * N * 3;
            const int i0 = faces[f * 3 + 0], i1 = faces[f * 3 + 1], i2 = faces[f * 3 + 2];
            float v0x = vb[i0 * 3], v0y = vb[i0 * 3 + 1], v0z = vb[i0 * 3 + 2];
            float v1x = vb[i1 * 3], v1y = vb[i1 * 3 + 1], v1z = vb[i1 * 3 + 2];
            float v2x = vb[i2 * 3], v2y = vb[i2 * 3 + 1], v2z = vb[i2 * 3 + 2];
            float ax = v1x - v2x, ay = v1y - v2y, az = v1z - v2z;
            float bx = v0x - v2x, by = v0y - v2y, bz = v0z - v2z;
            float cx = v0x - v1x, cy = v0y - v1y, cz = v0z - v1z;
            float A  = sqrtf(ax * ax + ay * ay + az * az);
            float Bl = sqrtf(bx * bx + by * by + bz * bz);
            float C  = sqrtf(cx * cx + cy * cy + cz * cz);
            float s2 = 0.5f * (A + Bl + C);
            float area = sqrtf(fmaxf(s2 * (s2 - A) * (s2 - Bl) * (s2 - C), 1e-12f));
            float A2 = A * A, B2 = Bl * Bl, C2 = C * C;
            float inv4a = 1.0f / (4.0f * area);
            float cota = (B2 + C2 - A2) * inv4a;
            float cotb = (A2 + C2 - B2) * inv4a;
            float cotc = (A2 + B2 - C2) * inv4a;

            float* __restrict__ Lb = Lx + (size_t)b * N * 3;
            float* __restrict__ rb = rowsum + (size_t)b * N;
            #define SCAT(i, j, wv)                                            \
                atomicAdd(&Lb[(i) * 3 + 0], (wv) * vb[(j) * 3 + 0]);          \
                atomicAdd(&Lb[(i) * 3 + 1], (wv) * vb[(j) * 3 + 1]);          \
                atomicAdd(&Lb[(i) * 3 + 2], (wv) * vb[(j) * 3 + 2]);          \
                atomicAdd(&rb[(i)], (wv));
            SCAT(i1, i2, cota) SCAT(i2, i1, cota)
            SCAT(i2, i0, cotb) SCAT(i0, i2, cotb)
            SCAT(i0, i1, cotc) SCAT(i1, i0, cotc)
            #undef SCAT
        }
    }
    se = wave_sum(se);
    sp = wave_sum(sp);
    if ((threadIdx.x & 63) == 0) atomicAdd(accum, fmaf(se, scaleE, sp * scaleP));
}

// rowpart 4-chunk min + clamp + lap residual; last block writes d_out.
__global__ void finalize_k(const float* __restrict__ rowpart,
                           const float* __restrict__ pred, const float* __restrict__ Lx,
                           const float* __restrict__ rowsum,
                           int N, float sMain, float sVel, float scaleL,
                           float* __restrict__ accum, float* __restrict__ out)
{
    const int total = 8 * N + 2 * N;
    float sm = 0.f, sv = 0.f, sl = 0.f;
    for (int idx = blockIdx.x * blockDim.x + threadIdx.x; idx < total;
         idx += gridDim.x * blockDim.x) {
        if (idx < 8 * N) {
            const int c = idx / N, i = idx - c * N;
            const int ds = (c >> 1) & 1;
            if (i < N - ds) {
                const float* rp = rowpart + (size_t)c * 4 * RSTRIDE;
                float v = fminf(fminf(rp[i], rp[RSTRIDE + i]),
                                fminf(rp[2*RSTRIDE + i], rp[3*RSTRIDE + i]));
                float d = fmaxf(v, 0.f);
                if (ds) sv += d; else sm += d;
            }
        } else {
            const int q = idx - 8 * N;       // B*N lap entries
            float rs = rowsum[q];
            float nw = rs > 0.f ? 1.0f / rs : 0.f;
            float rx = Lx[q*3+0]*nw - pred[q*3+0];
            float ry = Lx[q*3+1]*nw - pred[q*3+1];
            float rz = Lx[q*3+2]*nw - pred[q*3+2];
            sl += sqrtf(rx*rx + ry*ry + rz*rz);
        }
    }
    sm = wave_sum(sm); sv = wave_sum(sv); sl = wave_sum(sl);
    if ((threadIdx.x & 63) == 0)
        atomicAdd(accum, fmaf(sm, sMain, fmaf(sv, sVel, sl * scaleL)));

    // last block writes the output (accum[4] is the completion counter,
    // zeroed by bprep_k's ws-zero each launch)
    __syncthreads();
    if (threadIdx.x == 0){
        __threadfence();
        const uint32 prev = atomicAdd((uint32*)(accum + 4), 1u);
        if (prev == gridDim.x - 1)
            out[0] = atomicAdd(accum, 0.0f);   // coherent read of final sum
    }
}

extern "C" void kernel_launch(void* const* d_in, const int* in_sizes, int n_in,
                              void* d_out, int out_size, void* d_ws, size_t ws_size,
                              hipStream_t stream)
{
    const float* pred = (const float*)d_in[0];
    const float* tgt  = (const float*)d_in[1];
    const int* faces  = (const int*)d_in[2];
    const int* edges  = (const int*)d_in[3];
    const int* pairs  = (const int*)d_in[4];

    const int B = 2;
    const int N = in_sizes[0] / (3 * B);   // 8281
    const int F = in_sizes[2] / 3;
    const int E = in_sizes[3] / 2;
    const int P = in_sizes[4] / 4;
    const int NT = (N + 31) >> 5;          // 259

    // workspace layout (4B units):
    // [accum 8 (incl counter at +4)][Lx B*N*3][rowsum B*N][rowpart 32*RSTRIDE][bfrag]
    float* ws      = (float*)d_ws;
    float* accum   = ws;
    float* Lx      = ws + 8;
    float* rowsum  = Lx + (size_t)B * N * 3;
    float* rowpart = rowsum + (size_t)B * N;
    size_t off     = 8 + (size_t)B*N*3 + (size_t)B*N + (size_t)32*RSTRIDE;
    uint4* bfrag   = (uint4*)(ws + off);   // off*4 16B-aligned (off div by 4)

    const int nzero = 8 + B * N * 3 + B * N;

    bprep_k<<<dim3((8 * NT + 3) / 4), dim3(256), 0, stream>>>(pred, tgt, N, bfrag,
                                                              ws, nzero);

    chamfer_mfma_k<<<dim3((N + 127) / 128, 4, 8), dim3(256), 0, stream>>>(
        pred, tgt, N, bfrag, rowpart);

    mesh_k<<<128, dim3(256), 0, stream>>>(pred, edges, E, pairs, P, faces, F, N, B,
                                          W_EDGE / ((float)B * (float)E),
                                          W_NORMAL / ((float)B * (float)P),
                                          Lx, rowsum, accum);

    finalize_k<<<96, dim3(256), 0, stream>>>(rowpart, pred, Lx, rowsum, N,
                                             1.0f / ((float)B * (float)N),
                                             W_VEL / ((float)B * (float)(N - 1)),
                                             W_LAP / ((float)B * (float)N),
                                             accum, (float*)d_out);
}